// Round 3
// baseline (1172.589 us; speedup 1.0000x reference)
//
#include <hip/hip_runtime.h>
#include <hip/hip_fp16.h>
#include <math.h>

#define N_NODES 100000
#define N_EDGES 1600000
#define RR      6
#define CIN     8
#define COUT    16
#define EPS     1e-8f

#define NBLK_A  512
#define ABLOCK  1024
#define CHUNK   (N_EDGES / NBLK_A)      // 3125 (exact)
#define NBUCK   391                     // dst >> 8
#define RECCAP  4608                    // per-bucket cap (mean 4096, +8 sigma)

// Dynamic LDS layout for partition_kernel (manual offsets, all aligned):
//   spay : uint2[CHUNK*3]     75000 B  @ 0
//   shdr : uint [CHUNK]       12500 B  @ 75000
//   sbkt : ushort[CHUNK]       6250 B  @ 87500
//   cnt/cur/base/gbase : int[NBUCK]x4  @ 93752  (6256 B)
#define LDS_SPAY   0
#define LDS_SHDR   75000
#define LDS_SBKT   87500
#define LDS_CNT    93752
#define LDS_TOTAL  100032

// float pair -> packed fp16x2 (RNE)
__device__ inline unsigned int pack_f16(float a, float b) {
    __half2 h = __floats2half2_rn(a, b);
    return *(unsigned int*)&h;
}

// ---------------------------------------------------------------------------
// Phase A v3 (unchanged): all global accesses streaming/coalesced.
// ---------------------------------------------------------------------------
__global__ __launch_bounds__(ABLOCK)
void partition_kernel(const int* __restrict__ edges,
                      const float* __restrict__ sten,
                      int* __restrict__ gcur,
                      unsigned int* __restrict__ hdr,
                      unsigned int* __restrict__ pay) {
    extern __shared__ char smem[];
    uint2*          spay = (uint2*)(smem + LDS_SPAY);
    unsigned int*   shdr = (unsigned int*)(smem + LDS_SHDR);
    unsigned short* sbkt = (unsigned short*)(smem + LDS_SBKT);
    int* cnt   = (int*)(smem + LDS_CNT);
    int* cur   = cnt + NBUCK;
    int* base  = cur + NBUCK;
    int* gbase = base + NBUCK;

    int tid = threadIdx.x;
    int blk = blockIdx.x;
    int e0 = blk * CHUNK;

    for (int i = tid; i < NBUCK; i += ABLOCK) { cnt[i] = 0; cur[i] = 0; }
    __syncthreads();

    // pass 1: count buckets (coalesced streaming read of edges)
    for (int i = tid; i < CHUNK; i += ABLOCK) {
        int2 ed = ((const int2*)edges)[e0 + i];
        atomicAdd(&cnt[ed.y >> 8], 1);
    }
    __syncthreads();

    // exclusive scan cnt -> base (wave 0)
    if (tid < 64) {
        int lane = tid;
        int off = 0;
        for (int c = 0; c < NBUCK; c += 64) {
            int idx = c + lane;
            int v = (idx < NBUCK) ? cnt[idx] : 0;
            int orig = v;
#pragma unroll
            for (int d = 1; d < 64; d <<= 1) {
                int t = __shfl_up(v, d);
                if (lane >= d) v += t;
            }
            if (idx < NBUCK) base[idx] = off + v - orig;
            off += __shfl(v, 63);
        }
    }
    __syncthreads();

    // reserve global run per bucket
    for (int b = tid; b < NBUCK; b += ABLOCK) {
        int c = cnt[b];
        gbase[b] = (c > 0) ? atomicAdd(&gcur[b], c) : 0;
    }
    __syncthreads();

    // pass 2: edge-order place + stage (sten is a coalesced stream)
    for (int i = tid; i < CHUNK; i += ABLOCK) {
        int e = e0 + i;
        int2 ed = ((const int2*)edges)[e];
        int b = ed.y >> 8;
        int p = base[b] + atomicAdd(&cur[b], 1);
        sbkt[p] = (unsigned short)b;
        shdr[p] = ((unsigned int)ed.x << 8) | (unsigned int)(ed.y & 255);
        const float4* sp = (const float4*)(sten + (size_t)e * 12);
        float4 s0 = sp[0], s1 = sp[1], s2 = sp[2];
        uint2* dp = spay + p * 3;
        dp[0] = (uint2){ pack_f16(s0.x, s0.y), pack_f16(s0.z, s0.w) };
        dp[1] = (uint2){ pack_f16(s1.x, s1.y), pack_f16(s1.z, s1.w) };
        dp[2] = (uint2){ pack_f16(s2.x, s2.y), pack_f16(s2.z, s2.w) };
    }
    __syncthreads();

    // pass 3: drain in p-order -> sequential run writes
    for (int p = tid; p < CHUNK; p += ABLOCK) {
        int b = (int)sbkt[p];
        int rel = p - base[b];
        long long slot = (long long)gbase[b] + rel;
        if (slot < RECCAP) {
            size_t rs = (size_t)b * RECCAP + slot;
            hdr[rs] = shdr[p];
            const uint2* sp = spay + p * 3;
            uint2 w0 = sp[0], w1 = sp[1], w2 = sp[2];
            unsigned int* dp = pay + rs * 6;
            *(uint2*)(dp + 0) = w0;
            *(uint2*)(dp + 2) = w1;
            *(uint2*)(dp + 4) = w2;
        }
    }
}

// ---------------------------------------------------------------------------
// Phase B v4: edge-parallel LDS-atomic accumulate (no sort, no serial walk).
// One block per HALF-bucket (128 nodes). 512 threads stream the bucket's
// dense record run (coalesced hdr+pay), 4 lanes per record; each lane
// scatters its 24 message components into acc[node][comp] via ds_add_f32.
// Row stride 97 (96 == 0 mod 32 would serialize banks; 97 spreads by node).
// Epilogue: 4 lanes per node, einsum from LDS acc (same math as before).
// LDS: acc 49.7KB + fre/fim 6KB + bsh -> ~56KB -> 2 blocks/CU, 16 waves/CU.
// ---------------------------------------------------------------------------
__global__ __launch_bounds__(512, 4)
void bucket_kernel(const float* __restrict__ x,
                   const float* __restrict__ weight,
                   const float* __restrict__ offset,
                   const float* __restrict__ bias,
                   const int* __restrict__ gcur,
                   const unsigned int* __restrict__ hdr,
                   const unsigned int* __restrict__ pay,
                   float* __restrict__ out) {
    __shared__ float acc[128][97];              // 49,664 B
    __shared__ float fre[RR * CIN * COUT];
    __shared__ float fim[RR * CIN * COUT];
    __shared__ float bsh[COUT];

    int tid  = threadIdx.x;
    int b    = blockIdx.x >> 1;
    int half = blockIdx.x & 1;

    for (int i = tid; i < RR * CIN * COUT; i += 512) {
        int co = i % (CIN * COUT);              // offset is (CIN, COUT)
        float w = weight[i], off = offset[co];
        fre[i] = w * cosf(off);
        fim[i] = w * sinf(off);
    }
    if (tid < COUT) bsh[tid] = bias[tid];
    for (int i = tid; i < 128 * 97; i += 512) ((float*)acc)[i] = 0.f;
    __syncthreads();

    int T = gcur[b];
    if (T > RECCAP) T = RECCAP;

    const unsigned int* hslice = hdr + (size_t)b * RECCAP;
    const unsigned int* pslice = pay + (size_t)b * RECCAP * 6;

    int l = tid & 3;                            // lane handles c = 2l, 2l+1
    for (int jg = tid >> 2; jg < T; jg += 128) {
        unsigned int h = hslice[jg];            // coalesced (4-lane broadcast)
        int d8 = (int)(h & 255u);
        if ((d8 >> 7) == half) {
            int d = d8 & 127;
            const unsigned int* pp = pslice + (size_t)jg * 6;
            uint2 p0 = *(const uint2*)(pp + 0);
            uint2 p1 = *(const uint2*)(pp + 2);
            uint2 p2 = *(const uint2*)(pp + 4);
            int src = (int)(h >> 8);
            float2 xv = *(const float2*)(x + (size_t)src * CIN + 2 * l);
            unsigned int wv[6] = {p0.x, p0.y, p1.x, p1.y, p2.x, p2.y};
            float* accd = acc[d];
            int c4 = 4 * l;                     // comp base for c = 2l
#pragma unroll
            for (int r = 0; r < RR; ++r) {
                __half2 hh = *(__half2*)&wv[r];
                float sre = __half2float(__low2half(hh));
                float sim = __half2float(__high2half(hh));
                atomicAdd(&accd[r * 16 + c4 + 0], sre * xv.x);
                atomicAdd(&accd[r * 16 + c4 + 1], sim * xv.x);
                atomicAdd(&accd[r * 16 + c4 + 2], sre * xv.y);
                atomicAdd(&accd[r * 16 + c4 + 3], sim * xv.y);
            }
        }
    }
    __syncthreads();

    // epilogue: 4 lanes per node, einsum + mag/relu scale + coalesced write
    int local = tid >> 2;                       // 0..127
    int n = b * 256 + half * 128 + local;
    if (n >= N_NODES) return;

    float yr[COUT], yi[COUT];
#pragma unroll
    for (int o = 0; o < COUT; ++o) { yr[o] = 0.f; yi[o] = 0.f; }
#pragma unroll
    for (int r = 0; r < RR; ++r) {
#pragma unroll
        for (int j = 0; j < 2; ++j) {
            int c = 2 * l + j;
            float are = acc[local][r * 16 + c * 2 + 0];
            float aim = acc[local][r * 16 + c * 2 + 1];
            const float* fr = &fre[(r * CIN + c) * COUT];
            const float* fi = &fim[(r * CIN + c) * COUT];
#pragma unroll
            for (int o = 0; o < COUT; ++o) {
                yr[o] = fmaf(are, fr[o], yr[o]);
                yr[o] = fmaf(-aim, fi[o], yr[o]);
                yi[o] = fmaf(are, fi[o], yi[o]);
                yi[o] = fmaf(aim, fr[o], yi[o]);
            }
        }
    }
#pragma unroll
    for (int o = 0; o < COUT; ++o) {
        yr[o] += __shfl_xor(yr[o], 1);
        yr[o] += __shfl_xor(yr[o], 2);
        yi[o] += __shfl_xor(yi[o], 1);
        yi[o] += __shfl_xor(yi[o], 2);
    }
    float tmp[8];
    int ob = 4 * l;
#pragma unroll
    for (int j = 0; j < 4; ++j) {
        int o = ob + j;
        float re = yr[o], im = yi[o];
        float mag = sqrtf(re * re + im * im);
        float sc = fmaxf(mag + bsh[o], 0.f) / (mag + EPS);
        tmp[2 * j]     = re * sc;
        tmp[2 * j + 1] = im * sc;
    }
    float4* op = (float4*)(out + (size_t)n * 2 * COUT + 8 * l);
    op[0] = ((const float4*)tmp)[0];
    op[1] = ((const float4*)tmp)[1];
}

extern "C" void kernel_launch(void* const* d_in, const int* in_sizes, int n_in,
                              void* d_out, int out_size, void* d_ws, size_t ws_size,
                              hipStream_t stream) {
    const float* x      = (const float*)d_in[0];
    const int*   edges  = (const int*)d_in[1];
    const float* sten   = (const float*)d_in[2];
    const float* weight = (const float*)d_in[3];
    const float* offset = (const float*)d_in[4];
    const float* bias   = (const float*)d_in[5];
    float* out = (float*)d_out;

    // ws: gcur (4 KB) | hdr (NBUCK*RECCAP*4B = 7.2 MB) | pay (NBUCK*RECCAP*24B = 43.2 MB)
    int* gcur = (int*)d_ws;
    unsigned int* hdr = (unsigned int*)((char*)d_ws + 4096);
    unsigned int* pay = hdr + (size_t)NBUCK * RECCAP;

    // >64KB dynamic LDS needs the opt-in attribute (one-time, not a stream op)
    static int lds_inited = 0;
    if (!lds_inited) {
        (void)hipFuncSetAttribute((const void*)partition_kernel,
                                  hipFuncAttributeMaxDynamicSharedMemorySize,
                                  LDS_TOTAL);
        lds_inited = 1;
    }

    (void)hipMemsetAsync(gcur, 0, sizeof(int) * NBUCK, stream);

    partition_kernel<<<NBLK_A, ABLOCK, LDS_TOTAL, stream>>>(edges, sten, gcur, hdr, pay);
    bucket_kernel<<<NBUCK * 2, 512, 0, stream>>>(x, weight, offset, bias,
                                                 gcur, hdr, pay, out);
}

// Round 4
// 288.399 us; speedup vs baseline: 4.0659x; 4.0659x over previous
//
#include <hip/hip_runtime.h>
#include <hip/hip_fp16.h>
#include <math.h>

#define N_NODES 100000
#define N_EDGES 1600000
#define RR      6
#define CIN     8
#define COUT    16
#define EPS     1e-8f

#define NBLK_A  512
#define ABLOCK  1024
#define CHUNK   (N_EDGES / NBLK_A)      // 3125 (exact)
#define NBUCK   391                     // dst >> 8
#define RECCAP  4608                    // per-bucket cap (mean 4096, +8 sigma)
#define QCAP    1536                    // per-quarter cap

// Dynamic LDS layout for partition_kernel (manual offsets, all aligned):
//   spay : uint2[CHUNK*3]     75000 B  @ 0
//   shdr : uint [CHUNK]       12500 B  @ 75000
//   sbkt : ushort[CHUNK]       6250 B  @ 87500
//   cnt/cur/base/gbase : int[NBUCK]x4  @ 93752  (6256 B)
#define LDS_SPAY   0
#define LDS_SHDR   75000
#define LDS_SBKT   87500
#define LDS_CNT    93752
#define LDS_TOTAL  100032

// float pair -> packed fp16x2 (RNE)
__device__ inline unsigned int pack_f16(float a, float b) {
    __half2 h = __floats2half2_rn(a, b);
    return *(unsigned int*)&h;
}

// ---------------------------------------------------------------------------
// Phase A v3 (unchanged): all global accesses streaming/coalesced.
// ---------------------------------------------------------------------------
__global__ __launch_bounds__(ABLOCK)
void partition_kernel(const int* __restrict__ edges,
                      const float* __restrict__ sten,
                      int* __restrict__ gcur,
                      unsigned int* __restrict__ hdr,
                      unsigned int* __restrict__ pay) {
    extern __shared__ char smem[];
    uint2*          spay = (uint2*)(smem + LDS_SPAY);
    unsigned int*   shdr = (unsigned int*)(smem + LDS_SHDR);
    unsigned short* sbkt = (unsigned short*)(smem + LDS_SBKT);
    int* cnt   = (int*)(smem + LDS_CNT);
    int* cur   = cnt + NBUCK;
    int* base  = cur + NBUCK;
    int* gbase = base + NBUCK;

    int tid = threadIdx.x;
    int blk = blockIdx.x;
    int e0 = blk * CHUNK;

    for (int i = tid; i < NBUCK; i += ABLOCK) { cnt[i] = 0; cur[i] = 0; }
    __syncthreads();

    // pass 1: count buckets (coalesced streaming read of edges)
    for (int i = tid; i < CHUNK; i += ABLOCK) {
        int2 ed = ((const int2*)edges)[e0 + i];
        atomicAdd(&cnt[ed.y >> 8], 1);
    }
    __syncthreads();

    // exclusive scan cnt -> base (wave 0)
    if (tid < 64) {
        int lane = tid;
        int off = 0;
        for (int c = 0; c < NBUCK; c += 64) {
            int idx = c + lane;
            int v = (idx < NBUCK) ? cnt[idx] : 0;
            int orig = v;
#pragma unroll
            for (int d = 1; d < 64; d <<= 1) {
                int t = __shfl_up(v, d);
                if (lane >= d) v += t;
            }
            if (idx < NBUCK) base[idx] = off + v - orig;
            off += __shfl(v, 63);
        }
    }
    __syncthreads();

    // reserve global run per bucket
    for (int b = tid; b < NBUCK; b += ABLOCK) {
        int c = cnt[b];
        gbase[b] = (c > 0) ? atomicAdd(&gcur[b], c) : 0;
    }
    __syncthreads();

    // pass 2: edge-order place + stage (sten is a coalesced stream)
    for (int i = tid; i < CHUNK; i += ABLOCK) {
        int e = e0 + i;
        int2 ed = ((const int2*)edges)[e];
        int b = ed.y >> 8;
        int p = base[b] + atomicAdd(&cur[b], 1);
        sbkt[p] = (unsigned short)b;
        shdr[p] = ((unsigned int)ed.x << 8) | (unsigned int)(ed.y & 255);
        const float4* sp = (const float4*)(sten + (size_t)e * 12);
        float4 s0 = sp[0], s1 = sp[1], s2 = sp[2];
        uint2* dp = spay + p * 3;
        dp[0] = (uint2){ pack_f16(s0.x, s0.y), pack_f16(s0.z, s0.w) };
        dp[1] = (uint2){ pack_f16(s1.x, s1.y), pack_f16(s1.z, s1.w) };
        dp[2] = (uint2){ pack_f16(s2.x, s2.y), pack_f16(s2.z, s2.w) };
    }
    __syncthreads();

    // pass 3: drain in p-order -> sequential run writes
    for (int p = tid; p < CHUNK; p += ABLOCK) {
        int b = (int)sbkt[p];
        int rel = p - base[b];
        long long slot = (long long)gbase[b] + rel;
        if (slot < RECCAP) {
            size_t rs = (size_t)b * RECCAP + slot;
            hdr[rs] = shdr[p];
            const uint2* sp = spay + p * 3;
            uint2 w0 = sp[0], w1 = sp[1], w2 = sp[2];
            unsigned int* dp = pay + rs * 6;
            *(uint2*)(dp + 0) = w0;
            *(uint2*)(dp + 2) = w1;
            *(uint2*)(dp + 4) = w2;
        }
    }
}

// ---------------------------------------------------------------------------
// Phase B v5: round-2 structure (counting sort -> dense walk) with a 4-deep
// software prefetch in the consume loop. Statically-named slots (runtime-
// indexed reg arrays would spill to scratch). Out-of-range slots zero-fill
// so consume is branch-free (fp16 zero decodes to 0.0 -> FMA adds 0).
// ---------------------------------------------------------------------------
__global__ __launch_bounds__(256, 6)
void bucket_kernel(const float* __restrict__ x,
                   const float* __restrict__ weight,
                   const float* __restrict__ offset,
                   const float* __restrict__ bias,
                   const int* __restrict__ gcur,
                   const unsigned int* __restrict__ hdr,
                   const unsigned int* __restrict__ pay,
                   float* __restrict__ out) {
    __shared__ unsigned int idxs[QCAP];         // 6 KB: (src<<13) | j
    __shared__ int cnt[64], nbase[64], cur2[64];
    __shared__ float fre[RR * CIN * COUT];
    __shared__ float fim[RR * CIN * COUT];
    __shared__ float bsh[COUT];

    int tid = threadIdx.x;
    int b   = blockIdx.x >> 2;
    int q   = blockIdx.x & 3;

    for (int i = tid; i < RR * CIN * COUT; i += 256) {
        int co = i % (CIN * COUT);              // offset is (CIN, COUT)
        float w = weight[i], off = offset[co];
        fre[i] = w * cosf(off);
        fim[i] = w * sinf(off);
    }
    if (tid < COUT) bsh[tid] = bias[tid];
    if (tid < 64) { cnt[tid] = 0; cur2[tid] = 0; }
    __syncthreads();

    int T = gcur[b];
    if (T > RECCAP) T = RECCAP;

    const unsigned int* hslice = hdr + (size_t)b * RECCAP;

    // pass 1: dense, coalesced header read; count this quarter's nodes
    for (int j = tid; j < T; j += 256) {
        unsigned int h = hslice[j];
        int d = (int)(h & 255u);
        if ((d >> 6) == q) atomicAdd(&cnt[d & 63], 1);
    }
    __syncthreads();

    // exclusive scan of 64 counters (wave 0)
    if (tid < 64) {
        int v = cnt[tid];
        int orig = v;
#pragma unroll
        for (int d = 1; d < 64; d <<= 1) {
            int t = __shfl_up(v, d);
            if (tid >= d) v += t;
        }
        nbase[tid] = v - orig;
    }
    __syncthreads();

    // pass 2: re-read headers (L1-hot, 16KB slice); place packed (src<<13)|j
    for (int j = tid; j < T; j += 256) {
        unsigned int h = hslice[j];
        int d = (int)(h & 255u);
        if ((d >> 6) == q) {
            int dl = d & 63;
            int pos = nbase[dl] + atomicAdd(&cur2[dl], 1);
            if (pos < QCAP)
                idxs[pos] = ((h >> 8) << 13) | (unsigned int)j;
        }
    }
    __syncthreads();

    // compute: 64 nodes x 4 lanes, 4-deep prefetched walk
    int local = tid >> 2;
    int n = b * 256 + q * 64 + local;
    int l = tid & 3;
    if (n >= N_NODES) return;

    int deg  = cnt[local];
    int base = nbase[local];
    if (base + deg > QCAP) deg = (base < QCAP) ? (QCAP - base) : 0;

    float ar[RR][2] = {};
    float ai[RR][2] = {};

    uint2 a0_0, a1_0, a2_0; float2 x_0;
    uint2 a0_1, a1_1, a2_1; float2 x_1;
    uint2 a0_2, a1_2, a2_2; float2 x_2;
    uint2 a0_3, a1_3, a2_3; float2 x_3;

#define PREF(s, idx) do {                                                   \
        if ((idx) < deg) {                                                  \
            unsigned int pk = idxs[base + (idx)];                           \
            int j   = (int)(pk & 8191u);                                    \
            int src = (int)(pk >> 13);                                      \
            const unsigned int* pp = pay + ((size_t)b * RECCAP + j) * 6;    \
            a0_##s = *(const uint2*)(pp + 0);                               \
            a1_##s = *(const uint2*)(pp + 2);                               \
            a2_##s = *(const uint2*)(pp + 4);                               \
            x_##s  = *(const float2*)(x + (size_t)src * CIN + 2 * l);       \
        } else {                                                            \
            a0_##s = (uint2){0u, 0u}; a1_##s = (uint2){0u, 0u};             \
            a2_##s = (uint2){0u, 0u}; x_##s = (float2){0.f, 0.f};           \
        }                                                                   \
    } while (0)

#define CONS(s) do {                                                        \
        unsigned int wv[6] = {a0_##s.x, a0_##s.y, a1_##s.x,                 \
                              a1_##s.y, a2_##s.x, a2_##s.y};                \
        _Pragma("unroll")                                                   \
        for (int r = 0; r < RR; ++r) {                                      \
            __half2 hh = *(__half2*)&wv[r];                                 \
            float sre = __half2float(__low2half(hh));                       \
            float sim = __half2float(__high2half(hh));                      \
            ar[r][0] = fmaf(sre, x_##s.x, ar[r][0]);                        \
            ar[r][1] = fmaf(sre, x_##s.y, ar[r][1]);                        \
            ai[r][0] = fmaf(sim, x_##s.x, ai[r][0]);                        \
            ai[r][1] = fmaf(sim, x_##s.y, ai[r][1]);                        \
        }                                                                   \
    } while (0)

    PREF(0, 0); PREF(1, 1); PREF(2, 2); PREF(3, 3);
    for (int k = 0; k < deg; k += 4) {
        CONS(0); PREF(0, k + 4);
        CONS(1); PREF(1, k + 5);
        CONS(2); PREF(2, k + 6);
        CONS(3); PREF(3, k + 7);
    }
#undef PREF
#undef CONS

    float yr[COUT], yi[COUT];
#pragma unroll
    for (int o = 0; o < COUT; ++o) { yr[o] = 0.f; yi[o] = 0.f; }
#pragma unroll
    for (int r = 0; r < RR; ++r) {
#pragma unroll
        for (int j = 0; j < 2; ++j) {
            int c = 2 * l + j;
            float are = ar[r][j], aim = ai[r][j];
            const float* fr = &fre[(r * CIN + c) * COUT];
            const float* fi = &fim[(r * CIN + c) * COUT];
#pragma unroll
            for (int o = 0; o < COUT; ++o) {
                yr[o] = fmaf(are, fr[o], yr[o]);
                yr[o] = fmaf(-aim, fi[o], yr[o]);
                yi[o] = fmaf(are, fi[o], yi[o]);
                yi[o] = fmaf(aim, fr[o], yi[o]);
            }
        }
    }
#pragma unroll
    for (int o = 0; o < COUT; ++o) {
        yr[o] += __shfl_xor(yr[o], 1);
        yr[o] += __shfl_xor(yr[o], 2);
        yi[o] += __shfl_xor(yi[o], 1);
        yi[o] += __shfl_xor(yi[o], 2);
    }
    float tmp[8];
    int ob = 4 * l;
#pragma unroll
    for (int j = 0; j < 4; ++j) {
        int o = ob + j;
        float re = yr[o], im = yi[o];
        float mag = sqrtf(re * re + im * im);
        float sc = fmaxf(mag + bsh[o], 0.f) / (mag + EPS);
        tmp[2 * j]     = re * sc;
        tmp[2 * j + 1] = im * sc;
    }
    float4* op = (float4*)(out + (size_t)n * 2 * COUT + 8 * l);
    op[0] = ((const float4*)tmp)[0];
    op[1] = ((const float4*)tmp)[1];
}

extern "C" void kernel_launch(void* const* d_in, const int* in_sizes, int n_in,
                              void* d_out, int out_size, void* d_ws, size_t ws_size,
                              hipStream_t stream) {
    const float* x      = (const float*)d_in[0];
    const int*   edges  = (const int*)d_in[1];
    const float* sten   = (const float*)d_in[2];
    const float* weight = (const float*)d_in[3];
    const float* offset = (const float*)d_in[4];
    const float* bias   = (const float*)d_in[5];
    float* out = (float*)d_out;

    // ws: gcur (4 KB) | hdr (NBUCK*RECCAP*4B = 7.2 MB) | pay (NBUCK*RECCAP*24B = 43.2 MB)
    int* gcur = (int*)d_ws;
    unsigned int* hdr = (unsigned int*)((char*)d_ws + 4096);
    unsigned int* pay = hdr + (size_t)NBUCK * RECCAP;

    // >64KB dynamic LDS needs the opt-in attribute (one-time, not a stream op)
    static int lds_inited = 0;
    if (!lds_inited) {
        (void)hipFuncSetAttribute((const void*)partition_kernel,
                                  hipFuncAttributeMaxDynamicSharedMemorySize,
                                  LDS_TOTAL);
        lds_inited = 1;
    }

    (void)hipMemsetAsync(gcur, 0, sizeof(int) * NBUCK, stream);

    partition_kernel<<<NBLK_A, ABLOCK, LDS_TOTAL, stream>>>(edges, sten, gcur, hdr, pay);
    bucket_kernel<<<NBUCK * 4, 256, 0, stream>>>(x, weight, offset, bias,
                                                 gcur, hdr, pay, out);
}

// Round 5
// 220.096 us; speedup vs baseline: 5.3276x; 1.3103x over previous
//
#include <hip/hip_runtime.h>
#include <hip/hip_fp16.h>
#include <math.h>

#define N_NODES 100000
#define N_EDGES 1600000
#define RR      6
#define CIN     8
#define COUT    16
#define EPS     1e-8f

#define NBLK_A  512
#define ABLOCK  1024
#define CHUNK   (N_EDGES / NBLK_A)      // 3125 (exact)
#define NBUCK   391                     // dst >> 8
#define RECCAP  4608                    // per-bucket cap (mean 4096, +8 sigma)
#define QCAP    1536                    // per-quarter cap

// Dynamic LDS layout for partition_kernel (manual offsets, all aligned):
//   spay : uint2[CHUNK*3]     75000 B  @ 0
//   shdr : uint [CHUNK]       12500 B  @ 75000
//   sbkt : ushort[CHUNK]       6250 B  @ 87500
//   cnt/cur/base/gbase : int[NBUCK]x4  @ 93752  (6256 B)
#define LDS_SPAY   0
#define LDS_SHDR   75000
#define LDS_SBKT   87500
#define LDS_CNT    93752
#define LDS_TOTAL  100032

// float pair -> packed fp16x2 (RNE)
__device__ inline unsigned int pack_f16(float a, float b) {
    __half2 h = __floats2half2_rn(a, b);
    return *(unsigned int*)&h;
}

// ---------------------------------------------------------------------------
// Phase A v3 (unchanged): all global accesses streaming/coalesced.
// ---------------------------------------------------------------------------
__global__ __launch_bounds__(ABLOCK)
void partition_kernel(const int* __restrict__ edges,
                      const float* __restrict__ sten,
                      int* __restrict__ gcur,
                      unsigned int* __restrict__ hdr,
                      unsigned int* __restrict__ pay) {
    extern __shared__ char smem[];
    uint2*          spay = (uint2*)(smem + LDS_SPAY);
    unsigned int*   shdr = (unsigned int*)(smem + LDS_SHDR);
    unsigned short* sbkt = (unsigned short*)(smem + LDS_SBKT);
    int* cnt   = (int*)(smem + LDS_CNT);
    int* cur   = cnt + NBUCK;
    int* base  = cur + NBUCK;
    int* gbase = base + NBUCK;

    int tid = threadIdx.x;
    int blk = blockIdx.x;
    int e0 = blk * CHUNK;

    for (int i = tid; i < NBUCK; i += ABLOCK) { cnt[i] = 0; cur[i] = 0; }
    __syncthreads();

    // pass 1: count buckets (coalesced streaming read of edges)
    for (int i = tid; i < CHUNK; i += ABLOCK) {
        int2 ed = ((const int2*)edges)[e0 + i];
        atomicAdd(&cnt[ed.y >> 8], 1);
    }
    __syncthreads();

    // exclusive scan cnt -> base (wave 0)
    if (tid < 64) {
        int lane = tid;
        int off = 0;
        for (int c = 0; c < NBUCK; c += 64) {
            int idx = c + lane;
            int v = (idx < NBUCK) ? cnt[idx] : 0;
            int orig = v;
#pragma unroll
            for (int d = 1; d < 64; d <<= 1) {
                int t = __shfl_up(v, d);
                if (lane >= d) v += t;
            }
            if (idx < NBUCK) base[idx] = off + v - orig;
            off += __shfl(v, 63);
        }
    }
    __syncthreads();

    // reserve global run per bucket
    for (int b = tid; b < NBUCK; b += ABLOCK) {
        int c = cnt[b];
        gbase[b] = (c > 0) ? atomicAdd(&gcur[b], c) : 0;
    }
    __syncthreads();

    // pass 2: edge-order place + stage (sten is a coalesced stream)
    for (int i = tid; i < CHUNK; i += ABLOCK) {
        int e = e0 + i;
        int2 ed = ((const int2*)edges)[e];
        int b = ed.y >> 8;
        int p = base[b] + atomicAdd(&cur[b], 1);
        sbkt[p] = (unsigned short)b;
        shdr[p] = ((unsigned int)ed.x << 8) | (unsigned int)(ed.y & 255);
        const float4* sp = (const float4*)(sten + (size_t)e * 12);
        float4 s0 = sp[0], s1 = sp[1], s2 = sp[2];
        uint2* dp = spay + p * 3;
        dp[0] = (uint2){ pack_f16(s0.x, s0.y), pack_f16(s0.z, s0.w) };
        dp[1] = (uint2){ pack_f16(s1.x, s1.y), pack_f16(s1.z, s1.w) };
        dp[2] = (uint2){ pack_f16(s2.x, s2.y), pack_f16(s2.z, s2.w) };
    }
    __syncthreads();

    // pass 3: drain in p-order -> sequential run writes
    for (int p = tid; p < CHUNK; p += ABLOCK) {
        int b = (int)sbkt[p];
        int rel = p - base[b];
        long long slot = (long long)gbase[b] + rel;
        if (slot < RECCAP) {
            size_t rs = (size_t)b * RECCAP + slot;
            hdr[rs] = shdr[p];
            const uint2* sp = spay + p * 3;
            uint2 w0 = sp[0], w1 = sp[1], w2 = sp[2];
            unsigned int* dp = pay + rs * 6;
            *(uint2*)(dp + 0) = w0;
            *(uint2*)(dp + 2) = w1;
            *(uint2*)(dp + 4) = w2;
        }
    }
}

// ---------------------------------------------------------------------------
// Phase B v6: round-2 structure + 4-deep prefetch, now with VGPR headroom.
// __launch_bounds__(256, 4) -> 128-VGPR cap (was (256,6) -> ~85, which
// spilled the prefetch slots to scratch: WRITE_SIZE 14->144 MB in r4).
// Grid is ~6 blocks/CU so the lower occupancy bound costs nothing.
// unroll(disable) on the walk loop so the compiler doesn't double the
// live slot count.
// ---------------------------------------------------------------------------
__global__ __launch_bounds__(256, 4)
void bucket_kernel(const float* __restrict__ x,
                   const float* __restrict__ weight,
                   const float* __restrict__ offset,
                   const float* __restrict__ bias,
                   const int* __restrict__ gcur,
                   const unsigned int* __restrict__ hdr,
                   const unsigned int* __restrict__ pay,
                   float* __restrict__ out) {
    __shared__ unsigned int idxs[QCAP];         // 6 KB: (src<<13) | j
    __shared__ int cnt[64], nbase[64], cur2[64];
    __shared__ float fre[RR * CIN * COUT];
    __shared__ float fim[RR * CIN * COUT];
    __shared__ float bsh[COUT];

    int tid = threadIdx.x;
    int b   = blockIdx.x >> 2;
    int q   = blockIdx.x & 3;

    for (int i = tid; i < RR * CIN * COUT; i += 256) {
        int co = i % (CIN * COUT);              // offset is (CIN, COUT)
        float w = weight[i], off = offset[co];
        fre[i] = w * cosf(off);
        fim[i] = w * sinf(off);
    }
    if (tid < COUT) bsh[tid] = bias[tid];
    if (tid < 64) { cnt[tid] = 0; cur2[tid] = 0; }
    __syncthreads();

    int T = gcur[b];
    if (T > RECCAP) T = RECCAP;

    const unsigned int* hslice = hdr + (size_t)b * RECCAP;

    // pass 1: dense, coalesced header read; count this quarter's nodes
    for (int j = tid; j < T; j += 256) {
        unsigned int h = hslice[j];
        int d = (int)(h & 255u);
        if ((d >> 6) == q) atomicAdd(&cnt[d & 63], 1);
    }
    __syncthreads();

    // exclusive scan of 64 counters (wave 0)
    if (tid < 64) {
        int v = cnt[tid];
        int orig = v;
#pragma unroll
        for (int d = 1; d < 64; d <<= 1) {
            int t = __shfl_up(v, d);
            if (tid >= d) v += t;
        }
        nbase[tid] = v - orig;
    }
    __syncthreads();

    // pass 2: re-read headers (L1-hot, 16KB slice); place packed (src<<13)|j
    for (int j = tid; j < T; j += 256) {
        unsigned int h = hslice[j];
        int d = (int)(h & 255u);
        if ((d >> 6) == q) {
            int dl = d & 63;
            int pos = nbase[dl] + atomicAdd(&cur2[dl], 1);
            if (pos < QCAP)
                idxs[pos] = ((h >> 8) << 13) | (unsigned int)j;
        }
    }
    __syncthreads();

    // compute: 64 nodes x 4 lanes, 4-deep prefetched walk
    int local = tid >> 2;
    int n = b * 256 + q * 64 + local;
    int l = tid & 3;
    if (n >= N_NODES) return;

    int deg  = cnt[local];
    int base = nbase[local];
    if (base + deg > QCAP) deg = (base < QCAP) ? (QCAP - base) : 0;

    float ar[RR][2] = {};
    float ai[RR][2] = {};

    uint2 a0_0, a1_0, a2_0; float2 x_0;
    uint2 a0_1, a1_1, a2_1; float2 x_1;
    uint2 a0_2, a1_2, a2_2; float2 x_2;
    uint2 a0_3, a1_3, a2_3; float2 x_3;

#define PREF(s, idx) do {                                                   \
        if ((idx) < deg) {                                                  \
            unsigned int pk = idxs[base + (idx)];                           \
            int j   = (int)(pk & 8191u);                                    \
            int src = (int)(pk >> 13);                                      \
            const unsigned int* pp = pay + ((size_t)b * RECCAP + j) * 6;    \
            a0_##s = *(const uint2*)(pp + 0);                               \
            a1_##s = *(const uint2*)(pp + 2);                               \
            a2_##s = *(const uint2*)(pp + 4);                               \
            x_##s  = *(const float2*)(x + (size_t)src * CIN + 2 * l);       \
        } else {                                                            \
            a0_##s = (uint2){0u, 0u}; a1_##s = (uint2){0u, 0u};             \
            a2_##s = (uint2){0u, 0u}; x_##s = (float2){0.f, 0.f};           \
        }                                                                   \
    } while (0)

#define CONS(s) do {                                                        \
        unsigned int wv[6] = {a0_##s.x, a0_##s.y, a1_##s.x,                 \
                              a1_##s.y, a2_##s.x, a2_##s.y};                \
        _Pragma("unroll")                                                   \
        for (int r = 0; r < RR; ++r) {                                      \
            __half2 hh = *(__half2*)&wv[r];                                 \
            float sre = __half2float(__low2half(hh));                       \
            float sim = __half2float(__high2half(hh));                      \
            ar[r][0] = fmaf(sre, x_##s.x, ar[r][0]);                        \
            ar[r][1] = fmaf(sre, x_##s.y, ar[r][1]);                        \
            ai[r][0] = fmaf(sim, x_##s.x, ai[r][0]);                        \
            ai[r][1] = fmaf(sim, x_##s.y, ai[r][1]);                        \
        }                                                                   \
    } while (0)

    PREF(0, 0); PREF(1, 1); PREF(2, 2); PREF(3, 3);
#pragma clang loop unroll(disable)
    for (int k = 0; k < deg; k += 4) {
        CONS(0); PREF(0, k + 4);
        CONS(1); PREF(1, k + 5);
        CONS(2); PREF(2, k + 6);
        CONS(3); PREF(3, k + 7);
    }
#undef PREF
#undef CONS

    float yr[COUT], yi[COUT];
#pragma unroll
    for (int o = 0; o < COUT; ++o) { yr[o] = 0.f; yi[o] = 0.f; }
#pragma unroll
    for (int r = 0; r < RR; ++r) {
#pragma unroll
        for (int j = 0; j < 2; ++j) {
            int c = 2 * l + j;
            float are = ar[r][j], aim = ai[r][j];
            const float* fr = &fre[(r * CIN + c) * COUT];
            const float* fi = &fim[(r * CIN + c) * COUT];
#pragma unroll
            for (int o = 0; o < COUT; ++o) {
                yr[o] = fmaf(are, fr[o], yr[o]);
                yr[o] = fmaf(-aim, fi[o], yr[o]);
                yi[o] = fmaf(are, fi[o], yi[o]);
                yi[o] = fmaf(aim, fr[o], yi[o]);
            }
        }
    }
#pragma unroll
    for (int o = 0; o < COUT; ++o) {
        yr[o] += __shfl_xor(yr[o], 1);
        yr[o] += __shfl_xor(yr[o], 2);
        yi[o] += __shfl_xor(yi[o], 1);
        yi[o] += __shfl_xor(yi[o], 2);
    }
    float tmp[8];
    int ob = 4 * l;
#pragma unroll
    for (int j = 0; j < 4; ++j) {
        int o = ob + j;
        float re = yr[o], im = yi[o];
        float mag = sqrtf(re * re + im * im);
        float sc = fmaxf(mag + bsh[o], 0.f) / (mag + EPS);
        tmp[2 * j]     = re * sc;
        tmp[2 * j + 1] = im * sc;
    }
    float4* op = (float4*)(out + (size_t)n * 2 * COUT + 8 * l);
    op[0] = ((const float4*)tmp)[0];
    op[1] = ((const float4*)tmp)[1];
}

extern "C" void kernel_launch(void* const* d_in, const int* in_sizes, int n_in,
                              void* d_out, int out_size, void* d_ws, size_t ws_size,
                              hipStream_t stream) {
    const float* x      = (const float*)d_in[0];
    const int*   edges  = (const int*)d_in[1];
    const float* sten   = (const float*)d_in[2];
    const float* weight = (const float*)d_in[3];
    const float* offset = (const float*)d_in[4];
    const float* bias   = (const float*)d_in[5];
    float* out = (float*)d_out;

    // ws: gcur (4 KB) | hdr (NBUCK*RECCAP*4B = 7.2 MB) | pay (NBUCK*RECCAP*24B = 43.2 MB)
    int* gcur = (int*)d_ws;
    unsigned int* hdr = (unsigned int*)((char*)d_ws + 4096);
    unsigned int* pay = hdr + (size_t)NBUCK * RECCAP;

    // >64KB dynamic LDS needs the opt-in attribute (one-time, not a stream op)
    static int lds_inited = 0;
    if (!lds_inited) {
        (void)hipFuncSetAttribute((const void*)partition_kernel,
                                  hipFuncAttributeMaxDynamicSharedMemorySize,
                                  LDS_TOTAL);
        lds_inited = 1;
    }

    (void)hipMemsetAsync(gcur, 0, sizeof(int) * NBUCK, stream);

    partition_kernel<<<NBLK_A, ABLOCK, LDS_TOTAL, stream>>>(edges, sten, gcur, hdr, pay);
    bucket_kernel<<<NBUCK * 4, 256, 0, stream>>>(x, weight, offset, bias,
                                                 gcur, hdr, pay, out);
}